// Round 1
// baseline (75.486 us; speedup 1.0000x reference)
//
#include <hip/hip_runtime.h>
#include <math.h>

#define BB 4
#define HH 512
#define WW 512
#define HWSZ (HH * WW)
#define ROWS_BLOCKS 256              // 4 batches x 64 row-groups (8 rows each)

#define SK(x) ((x) + ((x) >> 5))     // LDS skew: 64 lanes -> 32 banks 2-way (free)

// ws layout:
//   [0,    128)    int flags[32]        (per pack-block: batch-slice has fg; 8/batch)
//   [512,  520)    double dacc          (global accumulator, init by pack)
//   [520,  524)    u32 done             (ticket counter, init by pack)
//   [32768, +128K) u32 cw[BB][16][512]  (bit i of cw[b][w][col] = mask at row 32w+i)

// ---------------------------------------------------------------------------
// Pass 1: bit-pack the target mask into column words. Thread (b,w,c4) reads
// 32 int4 down 4 adjacent columns (16B/lane, 1KB/instruction coalescing)
// -> one uint4 of column words. Presence flag per block via popc wave-reduce.
// Block 0 thread 0 also zero-inits the accumulator + ticket (safe: pack fully
// precedes rows on the stream).
// ---------------------------------------------------------------------------
__global__ __launch_bounds__(256) void pack_kernel(
    const int* __restrict__ target,
    unsigned int* __restrict__ cw,
    int* __restrict__ flags,
    double* __restrict__ dacc,
    unsigned int* __restrict__ done)
{
    __shared__ int sCnt;
    int q = blockIdx.x * 256 + threadIdx.x;   // 0..8191, one uint4 (4 cols) each
    int b = q >> 11;
    int rem = q & 2047;
    int w = rem >> 7;                // word-row 0..15
    int col = (rem & 127) << 2;      // first of 4 columns

    if (q == 0) { *dacc = 0.0; *done = 0u; }

    const int* t = target + b * HWSZ + (w << 5) * WW + col;
    unsigned int w0 = 0, w1 = 0, w2 = 0, w3 = 0;
#pragma unroll
    for (int i = 0; i < 32; ++i) {
        int4 v = *(const int4*)(t + i * WW);
        w0 |= (unsigned int)(v.x == 1) << i;
        w1 |= (unsigned int)(v.y == 1) << i;
        w2 |= (unsigned int)(v.z == 1) << i;
        w3 |= (unsigned int)(v.w == 1) << i;
    }
    ((uint4*)cw)[q] = make_uint4(w0, w1, w2, w3);

    int cnt = __popc(w0) + __popc(w1) + __popc(w2) + __popc(w3);
#pragma unroll
    for (int off = 32; off > 0; off >>= 1) cnt += __shfl_down(cnt, off, 64);
    if (threadIdx.x == 0) sCnt = 0;
    __syncthreads();
    if ((threadIdx.x & 63) == 0) atomicAdd(&sCnt, cnt);
    __syncthreads();
    if (threadIdx.x == 0) flags[blockIdx.x] = (sCnt > 0);
}

// ---------------------------------------------------------------------------
// Pass 2: 8 rows per block (one per wave). Stage A: load the batch's full
// 32 KB column-word mask into LDS (uint4). Stage B: exact per-(row,col)
// column distances gN,gP via clz/ctz on the own word + outward word loop.
// Stage C: sign-select expanding-ring search (exact), sigmoid weighting,
// 6-shuffle reduce. Finalize fused: per-block LDS reduce of the 8 wave sums,
// presence-gated double atomicAdd, last-block ticket writes out[0].
// ---------------------------------------------------------------------------
__global__ __launch_bounds__(512) void rows_kernel(
    const unsigned int* __restrict__ cw,
    const float* __restrict__ pred,
    const int* __restrict__ flags,
    double* __restrict__ dacc,
    unsigned int* __restrict__ done,
    float* __restrict__ out)
{
    __shared__ unsigned int sW[16 * 512];                 // 32 KB
    __shared__ float g2n[8][SK(511) + 1], g2p[8][SK(511) + 1];  // ~33.8 KB
    __shared__ float wsum[8];
    __shared__ int sPres;

    int blk = blockIdx.x;
    int b = blk >> 6;
    int g = blk & 63;                // row group
    int tid = threadIdx.x;
    int w = tid >> 6, lane = tid & 63;
    int row = 8 * g + w;             // this wave's image row
    int j0 = 8 * lane;               // this lane's ring-search columns

    // pred loads issued first (consumed in stage C)
    const float* p0 = pred + (b * 2 + 0) * HWSZ + row * WW + j0;
    const float* p1 = pred + (b * 2 + 1) * HWSZ + row * WW + j0;
    float4 a0 = *(const float4*)(p0);
    float4 a1 = *(const float4*)(p0 + 4);
    float4 c0 = *(const float4*)(p1);
    float4 c1 = *(const float4*)(p1 + 4);

    // per-batch presence (8 pack flags per batch), wave 0 only
    if (w == 0) {
        int f = (lane < 8) ? flags[b * 8 + lane] : 0;
        unsigned long long blt = __ballot(f != 0);
        if (lane == 0) sPres = (blt != 0ULL);  // visible after stage-A barrier
    }

    // ---- Stage A: batch mask -> LDS (coalesced, 4x uint4/thread)
    const uint4* cw4 = (const uint4*)(cw + b * 8192);
    uint4* sW4 = (uint4*)sW;
#pragma unroll
    for (int t = 0; t < 4; ++t)
        sW4[tid + 512 * t] = cw4[tid + 512 * t];
    __syncthreads();

    // ---- Stage B: build this row's g2n/g2p (lane covers cols lane+64t)
    int wr = row >> 5, bit = row & 31;
    float* G2N = g2n[w];
    float* G2P = g2p[w];
    unsigned int loMask = 0xFFFFFFFFu >> (31 - bit);   // bits 0..bit
    unsigned int hiMask = 0xFFFFFFFFu << bit;          // bits bit..31
#pragma unroll
    for (int t = 0; t < 8; ++t) {
        int col = lane + (t << 6);
        unsigned int Wr = sW[(wr << 9) + col];
        // --- N map (seed = mask)
        int dUp, dDn;
        unsigned int m = Wr & loMask;
        if (m) dUp = bit - (31 - __builtin_clz(m));
        else {
            dUp = 0x7FFFFFFF;
            for (int q = wr - 1; q >= 0; --q) {
                unsigned int W = sW[(q << 9) + col];
                if (W) { dUp = row - ((q << 5) + 31 - __builtin_clz(W)); break; }
            }
        }
        m = Wr & hiMask;
        if (m) dDn = __builtin_ctz(m) - bit;
        else {
            dDn = 0x7FFFFFFF;
            for (int q = wr + 1; q < 16; ++q) {
                unsigned int W = sW[(q << 9) + col];
                if (W) { dDn = (q << 5) + __builtin_ctz(W) - row; break; }
            }
        }
        int gN = min(dUp, dDn);
        G2N[SK(col)] = (gN > 511) ? 1e18f : (float)(gN * gN);
        // --- P map (seed = ~mask)
        unsigned int Vr = ~Wr;
        m = Vr & loMask;
        if (m) dUp = bit - (31 - __builtin_clz(m));
        else {
            dUp = 0x7FFFFFFF;
            for (int q = wr - 1; q >= 0; --q) {
                unsigned int W = ~sW[(q << 9) + col];
                if (W) { dUp = row - ((q << 5) + 31 - __builtin_clz(W)); break; }
            }
        }
        m = Vr & hiMask;
        if (m) dDn = __builtin_ctz(m) - bit;
        else {
            dDn = 0x7FFFFFFF;
            for (int q = wr + 1; q < 16; ++q) {
                unsigned int W = ~sW[(q << 9) + col];
                if (W) { dDn = (q << 5) + __builtin_ctz(W) - row; break; }
            }
        }
        int gP = min(dUp, dDn);
        G2P[SK(col)] = (gP > 511) ? 1e18f : (float)(gP * gP);
    }
    // G2N/G2P are wave-private and wave-coherent: no barrier needed.

    // ---- Stage C: sign-select ring search (R8-proven exact)
    const float* sel[8];
    float bs[8], sgn[8];
#pragma unroll
    for (int jj = 0; jj < 8; ++jj) {
        float on = G2N[SK(j0 + jj)];
        float op = G2P[SK(j0 + jj)];
        bool fg = (on == 0.0f);      // fg pixel -> neg_dist = 0, search pos
        sel[jj] = fg ? G2P : G2N;
        bs[jj]  = fg ? op : on;
        sgn[jj] = fg ? -1.0f : 1.0f; // dmap = neg - pos
    }
    for (int r = 1; r < WW; ++r) {
        float sq = (float)(r * r);
        float mx = 0.0f;
#pragma unroll
        for (int jj = 0; jj < 8; ++jj) mx = fmaxf(mx, bs[jj]);
        if (sq >= mx) break;         // exact early exit
#pragma unroll
        for (int jj = 0; jj < 8; ++jj) {
            int kl = j0 + jj - r; kl = kl < 0 ? 0 : kl;
            int kr = j0 + jj + r; kr = kr > (WW - 1) ? (WW - 1) : kr;
            bs[jj] = fminf(bs[jj], sq + sel[jj][SK(kl)]);
            bs[jj] = fminf(bs[jj], sq + sel[jj][SK(kr)]);
        }
    }

    float x0[8] = {a0.x, a0.y, a0.z, a0.w, a1.x, a1.y, a1.z, a1.w};
    float x1[8] = {c0.x, c0.y, c0.z, c0.w, c1.x, c1.y, c1.z, c1.w};
    float acc = 0.0f;
#pragma unroll
    for (int jj = 0; jj < 8; ++jj) {
        float dist = sgn[jj] * sqrtf(bs[jj]);                  // negEDT - posEDT
        float prob = 1.0f / (1.0f + __expf(x0[jj] - x1[jj]));  // softmax class-1
        acc += prob * dist;
    }
#pragma unroll
    for (int off = 32; off > 0; off >>= 1) acc += __shfl_down(acc, off, 64);

    // ---- fused finalize: block reduce -> one double atomic -> last-block out
    if (lane == 0) wsum[w] = acc;
    __syncthreads();
    if (tid == 0) {
        double s = 0.0;
#pragma unroll
        for (int i = 0; i < 8; ++i) s += (double)wsum[i];
        if (sPres) atomicAdd(dacc, s);       // presence guard ('mask.sum()>0')
        __threadfence();                     // order dacc add before ticket
        unsigned int t = atomicAdd(done, 1u);
        if (t == ROWS_BLOCKS - 1) {
            double tot = atomicAdd(dacc, 0.0);  // coherent read of final sum
            out[0] = (float)(tot * (1.0 / 2097152.0));  // mean over B*C*H*W
        }
    }
}

extern "C" void kernel_launch(void* const* d_in, const int* in_sizes, int n_in,
                              void* d_out, int out_size, void* d_ws, size_t ws_size,
                              hipStream_t stream) {
    const float* pred = (const float*)d_in[0];
    const int* target = (const int*)d_in[1];
    float* out = (float*)d_out;

    char* ws = (char*)d_ws;
    int* flags = (int*)(ws + 0);
    double* dacc = (double*)(ws + 512);
    unsigned int* done = (unsigned int*)(ws + 520);
    unsigned int* cw = (unsigned int*)(ws + 32768);

    pack_kernel<<<32, 256, 0, stream>>>(target, cw, flags, dacc, done);
    rows_kernel<<<ROWS_BLOCKS, 512, 0, stream>>>(cw, pred, flags, dacc, done, out);
}